// Round 2
// baseline (253.630 us; speedup 1.0000x reference)
//
#include <hip/hip_runtime.h>
#include <hip/hip_bf16.h>

typedef __bf16 bf16x8 __attribute__((ext_vector_type(8)));
typedef __bf16 bf16x4 __attribute__((ext_vector_type(4)));
typedef float  f32x4  __attribute__((ext_vector_type(4)));

#define MFMA16(a,b,c) __builtin_amdgcn_mfma_f32_16x16x32_bf16((a),(b),(c),0,0,0)

static constexpr int Tt = 256;   // seq len
static constexpr int Cc = 384;   // embed
static constexpr int Hh = 6;     // heads
static constexpr int Dd = 64;    // head dim
static constexpr int HD = 384;   // H*D
static constexpr int NQ = 1152;  // 3*H*D

// ---------------- prep: convert/transpose weights to bf16 ----------------
// wqkvb[n][c], n = which*384 + h*64 + d  (n-major rows of length C)
// wpb[co][ci] = wp[ci][co]
__global__ __launch_bounds__(256) void prep_w(
    const float* __restrict__ wq, const float* __restrict__ wk,
    const float* __restrict__ wv, const float* __restrict__ wp,
    __bf16* __restrict__ wqkvb, __bf16* __restrict__ wpb)
{
  int idx = blockIdx.x * 256 + threadIdx.x;
  const int n1 = NQ * Cc;  // 442368
  if (idx < n1) {
    int n = idx / Cc, c = idx % Cc;
    int which = n / HD, r = n % HD, h = r >> 6, d = r & 63;
    const float* w = which == 0 ? wq : (which == 1 ? wk : wv);
    wqkvb[idx] = (__bf16)w[(h * Cc + c) * Dd + d];
  } else {
    int j = idx - n1;
    if (j < Cc * HD) {
      int co = j / HD, ci = j % HD;
      wpb[j] = (__bf16)wp[ci * Cc + co];
    }
  }
}

// ---------------- GEMM 1: QKV projection ----------------
// x [Mc][384] fp32 (chunk base), wn [1152][384] bf16 -> qkv: 3 planes [Bc*6][256][64] bf16
__global__ __launch_bounds__(256) void gemm_qkv(
    const float* __restrict__ x, const __bf16* __restrict__ wn,
    __bf16* __restrict__ qkv, int Mc)
{
  __shared__ __align__(16) char smem[36864];
  __bf16* Al = (__bf16*)smem;              // [128][72] (144B stride)
  __bf16* Bl = (__bf16*)(smem + 18432);    // [128][72]

  const int tid = threadIdx.x;
  const int m0 = blockIdx.x * 128;
  const int n0 = blockIdx.y * 128;
  const int wid = tid >> 6, lane = tid & 63;
  const int wm = wid >> 1, wn_ = wid & 1;
  const int lr = lane & 15, lg = lane >> 4;

  f32x4 acc[4][4];
#pragma unroll
  for (int i = 0; i < 4; ++i)
#pragma unroll
    for (int j = 0; j < 4; ++j) acc[i][j] = f32x4{0.f, 0.f, 0.f, 0.f};

  for (int kt = 0; kt < Cc; kt += 64) {
    // stage A: 128x64 fp32 -> bf16
#pragma unroll
    for (int i = 0; i < 8; ++i) {
      int idx = tid + 256 * i;            // 2048 float4 chunks
      int row = idx >> 4, c4 = idx & 15;
      float4 v = *(const float4*)(x + (size_t)(m0 + row) * Cc + kt + c4 * 4);
      bf16x4 b; b[0] = (__bf16)v.x; b[1] = (__bf16)v.y; b[2] = (__bf16)v.z; b[3] = (__bf16)v.w;
      *(bf16x4*)((char*)Al + row * 144 + c4 * 8) = b;
    }
    // stage B: 128x64 bf16
#pragma unroll
    for (int i = 0; i < 4; ++i) {
      int idx = tid + 256 * i;            // 1024 bf16x8 chunks
      int row = idx >> 3, k8 = idx & 7;
      bf16x8 v = *(const bf16x8*)(wn + (size_t)(n0 + row) * Cc + kt + k8 * 8);
      *(bf16x8*)((char*)Bl + row * 144 + k8 * 16) = v;
    }
    __syncthreads();
#pragma unroll
    for (int ks = 0; ks < 2; ++ks) {
      bf16x8 af[4], bfr[4];
#pragma unroll
      for (int mi = 0; mi < 4; ++mi)
        af[mi] = *(const bf16x8*)((char*)Al + (wm * 64 + mi * 16 + lr) * 144 + ks * 64 + lg * 16);
#pragma unroll
      for (int ni = 0; ni < 4; ++ni)
        bfr[ni] = *(const bf16x8*)((char*)Bl + (wn_ * 64 + ni * 16 + lr) * 144 + ks * 64 + lg * 16);
#pragma unroll
      for (int mi = 0; mi < 4; ++mi)
#pragma unroll
        for (int ni = 0; ni < 4; ++ni)
          acc[mi][ni] = MFMA16(af[mi], bfr[ni], acc[mi][ni]);
    }
    __syncthreads();
  }

  // epilogue: stage C tile in LDS (reuse), then coalesced 16B stores
  __bf16* Cl = (__bf16*)smem;  // [128][136] (272B stride)
#pragma unroll
  for (int mi = 0; mi < 4; ++mi)
#pragma unroll
    for (int ni = 0; ni < 4; ++ni)
#pragma unroll
      for (int j = 0; j < 4; ++j) {
        int row = wm * 64 + mi * 16 + lg * 4 + j;
        int col = wn_ * 64 + ni * 16 + lr;
        *((__bf16*)((char*)Cl + row * 272 + col * 2)) = (__bf16)acc[mi][ni][j];
      }
  __syncthreads();
#pragma unroll
  for (int p = 0; p < 8; ++p) {
    int row = p * 16 + (tid >> 4);
    int ch = tid & 15;
    bf16x8 v = *(const bf16x8*)((char*)Cl + row * 272 + ch * 16);
    int m = m0 + row, n = n0 + ch * 8;
    int which = n / HD, r = n % HD, h = r >> 6, d = r & 63;
    int bl = m >> 8, t = m & 255;
    *(bf16x8*)(qkv + (size_t)which * ((size_t)Mc * HD) +
               ((size_t)(bl * Hh + h) * Tt + t) * Dd + d) = v;
  }
}

// ---------------- Attention: one block per (b,h) ----------------
__global__ __launch_bounds__(256) void attn_k(
    const __bf16* __restrict__ q, const __bf16* __restrict__ k,
    const __bf16* __restrict__ v, __bf16* __restrict__ att)
{
  __shared__ __align__(16) char smem[98304];
  char* Kl = smem;           // [256][64] bf16, byte ^ ((key&7)<<4)
  char* Vl = smem + 32768;   // [64][256] bf16 (transposed), byte ^ ((d&7)<<4)
  char* Pl = smem + 65536;   // per-wave [16][256] bf16, byte ^ ((q&7)<<4)

  const int bh = blockIdx.x;
  const int tid = threadIdx.x, wid = tid >> 6, lane = tid & 63;
  const int lr = lane & 15, lg = lane >> 4;
  const size_t base = (size_t)bh * (Tt * Dd);

  // stage K (swizzled row-major)
#pragma unroll
  for (int i = 0; i < 8; ++i) {
    int chunk = tid + 256 * i;           // 2048 chunks of 8 bf16
    int key = chunk >> 3, d8 = chunk & 7;
    bf16x8 kv = *(const bf16x8*)(k + base + key * 64 + d8 * 8);
    *(bf16x8*)(Kl + ((key * 128 + d8 * 16) ^ ((key & 7) << 4))) = kv;
  }
  // stage V transposed (scalar writes, swizzled)
#pragma unroll
  for (int i = 0; i < 8; ++i) {
    int chunk = tid + 256 * i;
    int key = chunk >> 3, d8 = chunk & 7;
    bf16x8 vv = *(const bf16x8*)(v + base + key * 64 + d8 * 8);
#pragma unroll
    for (int e = 0; e < 8; ++e) {
      int d = d8 * 8 + e;
      *(__bf16*)(Vl + ((d * 512 + key * 2) ^ ((d & 7) << 4))) = vv[e];
    }
  }
  __syncthreads();

  char* Pw = Pl + wid * 8192;
  const int bl = bh / Hh, h = bh % Hh;

  for (int qi = 0; qi < 4; ++qi) {
    const int qt = wid + qi * 4;        // q-tile index 0..15
    const int qbase = qt * 16;

    bf16x8 qf0 = *(const bf16x8*)(q + base + (qbase + lr) * 64 + lg * 8);
    bf16x8 qf1 = *(const bf16x8*)(q + base + (qbase + lr) * 64 + 32 + lg * 8);

    f32x4 s[16];
#pragma unroll
    for (int n = 0; n < 16; ++n) s[n] = f32x4{0.f, 0.f, 0.f, 0.f};
#pragma unroll
    for (int n = 0; n < 16; ++n) {
      if (n <= qt) {
        int rowb = (n * 16 + lr) * 128;
        int swz = (lr & 7) << 4;
        bf16x8 k0 = *(const bf16x8*)(Kl + ((rowb + lg * 16) ^ swz));
        bf16x8 k1 = *(const bf16x8*)(Kl + ((rowb + 64 + lg * 16) ^ swz));
        s[n] = MFMA16(qf0, k0, s[n]);
        s[n] = MFMA16(qf1, k1, s[n]);
      }
    }
    // scale + causal mask
#pragma unroll
    for (int n = 0; n < 16; ++n)
#pragma unroll
      for (int j = 0; j < 4; ++j) {
        int key = n * 16 + lr;
        int qrow = qbase + lg * 4 + j;
        s[n][j] = (n <= qt && key <= qrow) ? s[n][j] * 0.125f : -1e30f;
      }
    // softmax over keys (per row): in-lane over n, then 16-lane butterfly
    float m4[4] = {-1e30f, -1e30f, -1e30f, -1e30f};
#pragma unroll
    for (int n = 0; n < 16; ++n)
#pragma unroll
      for (int j = 0; j < 4; ++j) m4[j] = fmaxf(m4[j], s[n][j]);
#pragma unroll
    for (int j = 0; j < 4; ++j) {
      m4[j] = fmaxf(m4[j], __shfl_xor(m4[j], 1));
      m4[j] = fmaxf(m4[j], __shfl_xor(m4[j], 2));
      m4[j] = fmaxf(m4[j], __shfl_xor(m4[j], 4));
      m4[j] = fmaxf(m4[j], __shfl_xor(m4[j], 8));
    }
    float sum4[4] = {0.f, 0.f, 0.f, 0.f};
#pragma unroll
    for (int n = 0; n < 16; ++n)
#pragma unroll
      for (int j = 0; j < 4; ++j) {
        float p = __expf(s[n][j] - m4[j]);
        s[n][j] = p;
        sum4[j] += p;
      }
#pragma unroll
    for (int j = 0; j < 4; ++j) {
      sum4[j] += __shfl_xor(sum4[j], 1);
      sum4[j] += __shfl_xor(sum4[j], 2);
      sum4[j] += __shfl_xor(sum4[j], 4);
      sum4[j] += __shfl_xor(sum4[j], 8);
    }
    float inv4[4];
#pragma unroll
    for (int j = 0; j < 4; ++j) inv4[j] = 1.0f / sum4[j];

    // write P (zeros beyond causal limit), per-wave region
#pragma unroll
    for (int j = 0; j < 4; ++j) {
      int ql = lg * 4 + j;
      int rswz = (ql & 7) << 4;
#pragma unroll
      for (int n = 0; n < 16; ++n) {
        float p = s[n][j] * inv4[j];
        *(__bf16*)(Pw + ((ql * 512 + (n * 16 + lr) * 2) ^ rswz)) = (__bf16)p;
      }
    }
    asm volatile("s_waitcnt lgkmcnt(0)" ::: "memory");

    // PV
    f32x4 o[4];
#pragma unroll
    for (int dn = 0; dn < 4; ++dn) o[dn] = f32x4{0.f, 0.f, 0.f, 0.f};
    const int kkmax = (qbase + 15) >> 5;
#pragma unroll
    for (int kk = 0; kk < 8; ++kk) {
      if (kk <= kkmax) {
        bf16x8 pa = *(const bf16x8*)(Pw + ((lr * 512 + kk * 64 + lg * 16) ^ ((lr & 7) << 4)));
#pragma unroll
        for (int dn = 0; dn < 4; ++dn) {
          int d = dn * 16 + lr;
          bf16x8 vb = *(const bf16x8*)(Vl + ((d * 512 + kk * 64 + lg * 16) ^ ((d & 7) << 4)));
          o[dn] = MFMA16(pa, vb, o[dn]);
        }
      }
    }
    // write O -> att[(bl*256+qrow)*384 + h*64 + d]
#pragma unroll
    for (int dn = 0; dn < 4; ++dn)
#pragma unroll
      for (int j = 0; j < 4; ++j) {
        int qrow = qbase + lg * 4 + j;
        att[((size_t)(bl * Tt + qrow)) * HD + h * Dd + dn * 16 + lr] = (__bf16)o[dn][j];
      }
  }
}

// ---------------- GEMM 2: output projection + bias ----------------
__global__ __launch_bounds__(256) void gemm_out(
    const __bf16* __restrict__ att, const __bf16* __restrict__ wpb,
    const float* __restrict__ bp, float* __restrict__ out, int Mc)
{
  __shared__ __align__(16) char smem[36864];
  __bf16* Al = (__bf16*)smem;
  __bf16* Bl = (__bf16*)(smem + 18432);

  const int tid = threadIdx.x;
  const int m0 = blockIdx.x * 128;
  const int n0 = blockIdx.y * 128;
  const int wid = tid >> 6, lane = tid & 63;
  const int wm = wid >> 1, wn_ = wid & 1;
  const int lr = lane & 15, lg = lane >> 4;

  f32x4 acc[4][4];
#pragma unroll
  for (int i = 0; i < 4; ++i)
#pragma unroll
    for (int j = 0; j < 4; ++j) acc[i][j] = f32x4{0.f, 0.f, 0.f, 0.f};

  for (int kt = 0; kt < Cc; kt += 64) {
#pragma unroll
    for (int i = 0; i < 4; ++i) {
      int idx = tid + 256 * i;
      int row = idx >> 3, k8 = idx & 7;
      bf16x8 v = *(const bf16x8*)(att + (size_t)(m0 + row) * Cc + kt + k8 * 8);
      *(bf16x8*)((char*)Al + row * 144 + k8 * 16) = v;
    }
#pragma unroll
    for (int i = 0; i < 4; ++i) {
      int idx = tid + 256 * i;
      int row = idx >> 3, k8 = idx & 7;
      bf16x8 v = *(const bf16x8*)(wpb + (size_t)(n0 + row) * Cc + kt + k8 * 8);
      *(bf16x8*)((char*)Bl + row * 144 + k8 * 16) = v;
    }
    __syncthreads();
#pragma unroll
    for (int ks = 0; ks < 2; ++ks) {
      bf16x8 af[4], bfr[4];
#pragma unroll
      for (int mi = 0; mi < 4; ++mi)
        af[mi] = *(const bf16x8*)((char*)Al + (wm * 64 + mi * 16 + lr) * 144 + ks * 64 + lg * 16);
#pragma unroll
      for (int ni = 0; ni < 4; ++ni)
        bfr[ni] = *(const bf16x8*)((char*)Bl + (wn_ * 64 + ni * 16 + lr) * 144 + ks * 64 + lg * 16);
#pragma unroll
      for (int mi = 0; mi < 4; ++mi)
#pragma unroll
        for (int ni = 0; ni < 4; ++ni)
          acc[mi][ni] = MFMA16(af[mi], bfr[ni], acc[mi][ni]);
    }
    __syncthreads();
  }
#pragma unroll
  for (int ni = 0; ni < 4; ++ni) {
    int n = n0 + wn_ * 64 + ni * 16 + lr;
    float bv = bp[n];
#pragma unroll
    for (int mi = 0; mi < 4; ++mi)
#pragma unroll
      for (int j = 0; j < 4; ++j) {
        int m = m0 + wm * 64 + mi * 16 + lg * 4 + j;
        out[(size_t)m * Cc + n] = acc[mi][ni][j] + bv;
      }
  }
}

// ---------------- launch ----------------
extern "C" void kernel_launch(void* const* d_in, const int* in_sizes, int n_in,
                              void* d_out, int out_size, void* d_ws, size_t ws_size,
                              hipStream_t stream) {
  const float* x  = (const float*)d_in[0];
  const float* wq = (const float*)d_in[1];
  const float* wk = (const float*)d_in[2];
  const float* wv = (const float*)d_in[3];
  const float* wp = (const float*)d_in[4];
  const float* bp = (const float*)d_in[5];
  float* out = (float*)d_out;

  char* ws = (char*)d_ws;
  __bf16* wqkvb = (__bf16*)ws;                    // 884736 B
  __bf16* wpb   = (__bf16*)(ws + 884736);         // 294912 B
  char*   dyn   = ws + 1179648;

  // batch chunking so intermediates fit ws: per-chunk bytes = Bc*786432
  int Bc = 128;
  while (Bc > 1 && 1179648ull + (unsigned long long)Bc * 786432ull > (unsigned long long)ws_size)
    Bc >>= 1;
  const int Mc = Bc * 256;
  __bf16* qkv = (__bf16*)dyn;                             // 3 planes of Mc*384 bf16
  __bf16* att = (__bf16*)(dyn + (size_t)3 * Mc * HD * 2); // Mc*384 bf16

  prep_w<<<2304, 256, 0, stream>>>(wq, wk, wv, wp, wqkvb, wpb);

  for (int b0 = 0; b0 < 128; b0 += Bc) {
    const float* xc  = x + (size_t)b0 * Tt * Cc;
    float* outc      = out + (size_t)b0 * Tt * Cc;
    gemm_qkv<<<dim3(Mc / 128, 9), 256, 0, stream>>>(xc, wqkvb, qkv, Mc);
    attn_k<<<Bc * Hh, 256, 0, stream>>>(qkv, qkv + (size_t)Mc * HD,
                                        qkv + (size_t)2 * Mc * HD, att);
    gemm_out<<<dim3(Mc / 128, 3), 256, 0, stream>>>(att, wpb, bp, outc, Mc);
  }
}

// Round 3
// 218.467 us; speedup vs baseline: 1.1610x; 1.1610x over previous
//
#include <hip/hip_runtime.h>
#include <hip/hip_bf16.h>

typedef __bf16 bf16x8 __attribute__((ext_vector_type(8)));
typedef __bf16 bf16x4 __attribute__((ext_vector_type(4)));
typedef float  f32x4  __attribute__((ext_vector_type(4)));

#define MFMA16(a,b,c) __builtin_amdgcn_mfma_f32_16x16x32_bf16((a),(b),(c),0,0,0)

static constexpr int Tt = 256;   // seq len
static constexpr int Cc = 384;   // embed
static constexpr int Hh = 6;     // heads
static constexpr int Dd = 64;    // head dim
static constexpr int HD = 384;   // H*D
static constexpr int NQ = 1152;  // 3*H*D

// async global->LDS, 16B per lane; lds base must be wave-uniform
__device__ __forceinline__ void gload16(const void* g, void* l) {
  __builtin_amdgcn_global_load_lds(
      (const __attribute__((address_space(1))) void*)g,
      (__attribute__((address_space(3))) void*)l, 16, 0, 0);
}

// ---------------- xcast: x fp32 -> bf16 ----------------
__global__ __launch_bounds__(256) void xcast(
    const float* __restrict__ x, __bf16* __restrict__ xb)
{
  size_t i = (size_t)blockIdx.x * 256 + threadIdx.x;
  const float4* p = (const float4*)(x + i * 8);
  float4 a = p[0], b = p[1];
  bf16x8 o;
  o[0] = (__bf16)a.x; o[1] = (__bf16)a.y; o[2] = (__bf16)a.z; o[3] = (__bf16)a.w;
  o[4] = (__bf16)b.x; o[5] = (__bf16)b.y; o[6] = (__bf16)b.z; o[7] = (__bf16)b.w;
  *(bf16x8*)(xb + i * 8) = o;
}

// ---------------- prep: convert/transpose weights to bf16 ----------------
__global__ __launch_bounds__(256) void prep_w(
    const float* __restrict__ wq, const float* __restrict__ wk,
    const float* __restrict__ wv, const float* __restrict__ wp,
    __bf16* __restrict__ wqkvb, __bf16* __restrict__ wpb)
{
  int idx = blockIdx.x * 256 + threadIdx.x;
  const int n1 = NQ * Cc;  // 442368
  if (idx < n1) {
    int n = idx / Cc, c = idx % Cc;
    int which = n / HD, r = n % HD, h = r >> 6, d = r & 63;
    const float* w = which == 0 ? wq : (which == 1 ? wk : wv);
    wqkvb[idx] = (__bf16)w[(h * Cc + c) * Dd + d];
  } else {
    int j = idx - n1;
    if (j < Cc * HD) {
      int co = j / HD, ci = j % HD;
      wpb[j] = (__bf16)wp[ci * Cc + co];
    }
  }
}

// ---------------- GEMM 1: QKV projection (bf16 A via global_load_lds) ----------------
// xb [Mc][384] bf16, wn [1152][384] bf16 -> qkv: 3 planes [Bc*6][256][64] bf16
__global__ __launch_bounds__(256) void gemm_qkv(
    const __bf16* __restrict__ xb, const __bf16* __restrict__ wn,
    __bf16* __restrict__ qkv, int Mc)
{
  __shared__ __align__(16) char smem[36864];
  char* Al = smem;            // [128 rows][128B], slot s holds global slot s^(row&7)
  char* Bl = smem + 16384;

  const int tid = threadIdx.x;
  const int m0 = blockIdx.x * 128;
  const int n0 = blockIdx.y * 128;
  const int wid = tid >> 6, ln = tid & 63;
  const int wm = wid >> 1, wn_ = wid & 1;
  const int lr = ln & 15, lg = ln >> 4;
  const int srow = ln >> 3, sslot = ln & 7;

  f32x4 acc[4][4];
#pragma unroll
  for (int i = 0; i < 4; ++i)
#pragma unroll
    for (int j = 0; j < 4; ++j) acc[i][j] = f32x4{0.f, 0.f, 0.f, 0.f};

  for (int kt = 0; kt < Cc; kt += 64) {
#pragma unroll
    for (int i = 0; i < 4; ++i) {
      int off = (wid * 4 + i) << 10;
      int row = (off >> 7) + srow;
      gload16(xb + (size_t)(m0 + row) * Cc + kt + ((sslot ^ (row & 7)) << 3), Al + off);
    }
#pragma unroll
    for (int i = 0; i < 4; ++i) {
      int off = (wid * 4 + i) << 10;
      int row = (off >> 7) + srow;
      gload16(wn + (size_t)(n0 + row) * Cc + kt + ((sslot ^ (row & 7)) << 3), Bl + off);
    }
    __syncthreads();
#pragma unroll
    for (int ks = 0; ks < 2; ++ks) {
      bf16x8 af[4], bfr[4];
#pragma unroll
      for (int mi = 0; mi < 4; ++mi) {
        int r = wm * 64 + mi * 16 + lr;
        af[mi] = *(const bf16x8*)(Al + r * 128 + (((ks * 4 + lg) ^ (r & 7)) << 4));
      }
#pragma unroll
      for (int ni = 0; ni < 4; ++ni) {
        int r = wn_ * 64 + ni * 16 + lr;
        bfr[ni] = *(const bf16x8*)(Bl + r * 128 + (((ks * 4 + lg) ^ (r & 7)) << 4));
      }
      __builtin_amdgcn_s_setprio(1);
#pragma unroll
      for (int mi = 0; mi < 4; ++mi)
#pragma unroll
        for (int ni = 0; ni < 4; ++ni)
          acc[mi][ni] = MFMA16(af[mi], bfr[ni], acc[mi][ni]);
      __builtin_amdgcn_s_setprio(0);
    }
    __syncthreads();
  }

  // epilogue: stage C tile in LDS, then coalesced 16B scatter-stores
  __bf16* Cl = (__bf16*)smem;  // [128][136] (272B stride), 34816 B
#pragma unroll
  for (int mi = 0; mi < 4; ++mi)
#pragma unroll
    for (int ni = 0; ni < 4; ++ni)
#pragma unroll
      for (int j = 0; j < 4; ++j) {
        int row = wm * 64 + mi * 16 + lg * 4 + j;
        int col = wn_ * 64 + ni * 16 + lr;
        *((__bf16*)((char*)Cl + row * 272 + col * 2)) = (__bf16)acc[mi][ni][j];
      }
  __syncthreads();
#pragma unroll
  for (int p = 0; p < 8; ++p) {
    int row = p * 16 + (tid >> 4);
    int ch = tid & 15;
    bf16x8 v = *(const bf16x8*)((char*)Cl + row * 272 + ch * 16);
    int m = m0 + row, n = n0 + ch * 8;
    int which = n / HD, r = n % HD, h = r >> 6, d = r & 63;
    int bl = m >> 8, t = m & 255;
    *(bf16x8*)(qkv + (size_t)which * ((size_t)Mc * HD) +
               ((size_t)(bl * Hh + h) * Tt + t) * Dd + d) = v;
  }
}

// ---------------- Attention: one block (8 waves) per (b,h) ----------------
__global__ __launch_bounds__(512) void attn_k(
    const __bf16* __restrict__ q, const __bf16* __restrict__ k,
    const __bf16* __restrict__ v, __bf16* __restrict__ att)
{
  __shared__ __align__(16) char smem[131072];
  char* Kl = smem;           // [256][64] bf16, slot s holds global slot s^(key&7)
  char* Vl = smem + 32768;   // [64][256] bf16 (transposed), byte ^ ((d&7)<<4)
  char* Pl = smem + 65536;   // per-wave [16][256] bf16, byte ^ ((q&7)<<4)

  const int bh = blockIdx.x;
  const int tid = threadIdx.x, wid = tid >> 6, lane = tid & 63;
  const int lr = lane & 15, lg = lane >> 4;
  const size_t base = (size_t)bh * (Tt * Dd);

  // stage K via global_load_lds (linear dest, pre-swizzled source)
#pragma unroll
  for (int i = 0; i < 4; ++i) {
    int off = (wid * 4 + i) << 10;
    int row = (off >> 7) + (lane >> 3);
    int slot = lane & 7;
    gload16(k + base + row * 64 + ((slot ^ (row & 7)) << 3), Kl + off);
  }
  // stage V transposed (scalar writes, swizzled)
#pragma unroll
  for (int i = 0; i < 4; ++i) {
    int chunk = tid + 512 * i;           // 2048 chunks of 8 bf16
    int key = chunk >> 3, d8 = chunk & 7;
    bf16x8 vv = *(const bf16x8*)(v + base + key * 64 + d8 * 8);
#pragma unroll
    for (int e = 0; e < 8; ++e) {
      int d = d8 * 8 + e;
      *(__bf16*)(Vl + ((d * 512 + key * 2) ^ ((d & 7) << 4))) = vv[e];
    }
  }
  __syncthreads();

  char* Pw = Pl + wid * 8192;
  const int bl = bh / Hh, h = bh % Hh;

  for (int qi = 0; qi < 2; ++qi) {
    const int qt = qi == 0 ? wid : 15 - wid;   // q-tile index 0..15, balanced pairing
    const int qbase = qt * 16;

    bf16x8 qf0 = *(const bf16x8*)(q + base + (qbase + lr) * 64 + lg * 8);
    bf16x8 qf1 = *(const bf16x8*)(q + base + (qbase + lr) * 64 + 32 + lg * 8);

    f32x4 s[16];
#pragma unroll
    for (int n = 0; n < 16; ++n) s[n] = f32x4{0.f, 0.f, 0.f, 0.f};
    __builtin_amdgcn_s_setprio(1);
#pragma unroll
    for (int n = 0; n < 16; ++n) {
      if (n <= qt) {
        int rowb = (n * 16 + lr) * 128;
        int swz = (lr & 7) << 4;
        bf16x8 k0 = *(const bf16x8*)(Kl + ((rowb + lg * 16) ^ swz));
        bf16x8 k1 = *(const bf16x8*)(Kl + ((rowb + 64 + lg * 16) ^ swz));
        s[n] = MFMA16(qf0, k0, s[n]);
        s[n] = MFMA16(qf1, k1, s[n]);
      }
    }
    __builtin_amdgcn_s_setprio(0);
    // scale + causal mask
#pragma unroll
    for (int n = 0; n < 16; ++n)
#pragma unroll
      for (int j = 0; j < 4; ++j) {
        int key = n * 16 + lr;
        int qrow = qbase + lg * 4 + j;
        s[n][j] = (n <= qt && key <= qrow) ? s[n][j] * 0.125f : -1e30f;
      }
    // softmax over keys: in-lane over n, then 16-lane butterfly
    float m4[4] = {-1e30f, -1e30f, -1e30f, -1e30f};
#pragma unroll
    for (int n = 0; n < 16; ++n)
#pragma unroll
      for (int j = 0; j < 4; ++j) m4[j] = fmaxf(m4[j], s[n][j]);
#pragma unroll
    for (int j = 0; j < 4; ++j) {
      m4[j] = fmaxf(m4[j], __shfl_xor(m4[j], 1));
      m4[j] = fmaxf(m4[j], __shfl_xor(m4[j], 2));
      m4[j] = fmaxf(m4[j], __shfl_xor(m4[j], 4));
      m4[j] = fmaxf(m4[j], __shfl_xor(m4[j], 8));
    }
    float sum4[4] = {0.f, 0.f, 0.f, 0.f};
#pragma unroll
    for (int n = 0; n < 16; ++n)
#pragma unroll
      for (int j = 0; j < 4; ++j) {
        float p = __expf(s[n][j] - m4[j]);
        s[n][j] = p;
        sum4[j] += p;
      }
#pragma unroll
    for (int j = 0; j < 4; ++j) {
      sum4[j] += __shfl_xor(sum4[j], 1);
      sum4[j] += __shfl_xor(sum4[j], 2);
      sum4[j] += __shfl_xor(sum4[j], 4);
      sum4[j] += __shfl_xor(sum4[j], 8);
    }
    float inv4[4];
#pragma unroll
    for (int j = 0; j < 4; ++j) inv4[j] = 1.0f / sum4[j];

    // write P (zeros beyond causal limit), per-wave region
#pragma unroll
    for (int j = 0; j < 4; ++j) {
      int ql = lg * 4 + j;
      int rswz = (ql & 7) << 4;
#pragma unroll
      for (int n = 0; n < 16; ++n) {
        float p = s[n][j] * inv4[j];
        *(__bf16*)(Pw + ((ql * 512 + (n * 16 + lr) * 2) ^ rswz)) = (__bf16)p;
      }
    }
    asm volatile("s_waitcnt lgkmcnt(0)" ::: "memory");

    // PV
    f32x4 o[4];
#pragma unroll
    for (int dn = 0; dn < 4; ++dn) o[dn] = f32x4{0.f, 0.f, 0.f, 0.f};
    const int kkmax = (qbase + 15) >> 5;
    __builtin_amdgcn_s_setprio(1);
#pragma unroll
    for (int kk = 0; kk < 8; ++kk) {
      if (kk <= kkmax) {
        bf16x8 pa = *(const bf16x8*)(Pw + ((lr * 512 + kk * 64 + lg * 16) ^ ((lr & 7) << 4)));
#pragma unroll
        for (int dn = 0; dn < 4; ++dn) {
          int d = dn * 16 + lr;
          bf16x8 vb = *(const bf16x8*)(Vl + ((d * 512 + kk * 64 + lg * 16) ^ ((d & 7) << 4)));
          o[dn] = MFMA16(pa, vb, o[dn]);
        }
      }
    }
    __builtin_amdgcn_s_setprio(0);
    // write O -> att[(bl*256+qrow)*384 + h*64 + d]
#pragma unroll
    for (int dn = 0; dn < 4; ++dn)
#pragma unroll
      for (int j = 0; j < 4; ++j) {
        int qrow = qbase + lg * 4 + j;
        att[((size_t)(bl * Tt + qrow)) * HD + h * Dd + dn * 16 + lr] = (__bf16)o[dn][j];
      }
  }
}

// ---------------- GEMM 2: output projection + bias ----------------
__global__ __launch_bounds__(256) void gemm_out(
    const __bf16* __restrict__ att, const __bf16* __restrict__ wpb,
    const float* __restrict__ bp, float* __restrict__ out, int Mc)
{
  __shared__ __align__(16) char smem[32768];
  char* Al = smem;
  char* Bl = smem + 16384;

  const int tid = threadIdx.x;
  const int m0 = blockIdx.x * 128;
  const int n0 = blockIdx.y * 128;
  const int wid = tid >> 6, ln = tid & 63;
  const int wm = wid >> 1, wn_ = wid & 1;
  const int lr = ln & 15, lg = ln >> 4;
  const int srow = ln >> 3, sslot = ln & 7;

  f32x4 acc[4][4];
#pragma unroll
  for (int i = 0; i < 4; ++i)
#pragma unroll
    for (int j = 0; j < 4; ++j) acc[i][j] = f32x4{0.f, 0.f, 0.f, 0.f};

  for (int kt = 0; kt < Cc; kt += 64) {
#pragma unroll
    for (int i = 0; i < 4; ++i) {
      int off = (wid * 4 + i) << 10;
      int row = (off >> 7) + srow;
      gload16(att + (size_t)(m0 + row) * Cc + kt + ((sslot ^ (row & 7)) << 3), Al + off);
    }
#pragma unroll
    for (int i = 0; i < 4; ++i) {
      int off = (wid * 4 + i) << 10;
      int row = (off >> 7) + srow;
      gload16(wpb + (size_t)(n0 + row) * Cc + kt + ((sslot ^ (row & 7)) << 3), Bl + off);
    }
    __syncthreads();
#pragma unroll
    for (int ks = 0; ks < 2; ++ks) {
      bf16x8 af[4], bfr[4];
#pragma unroll
      for (int mi = 0; mi < 4; ++mi) {
        int r = wm * 64 + mi * 16 + lr;
        af[mi] = *(const bf16x8*)(Al + r * 128 + (((ks * 4 + lg) ^ (r & 7)) << 4));
      }
#pragma unroll
      for (int ni = 0; ni < 4; ++ni) {
        int r = wn_ * 64 + ni * 16 + lr;
        bfr[ni] = *(const bf16x8*)(Bl + r * 128 + (((ks * 4 + lg) ^ (r & 7)) << 4));
      }
      __builtin_amdgcn_s_setprio(1);
#pragma unroll
      for (int mi = 0; mi < 4; ++mi)
#pragma unroll
        for (int ni = 0; ni < 4; ++ni)
          acc[mi][ni] = MFMA16(af[mi], bfr[ni], acc[mi][ni]);
      __builtin_amdgcn_s_setprio(0);
    }
    __syncthreads();
  }
#pragma unroll
  for (int ni = 0; ni < 4; ++ni) {
    int n = n0 + wn_ * 64 + ni * 16 + lr;
    float bv = bp[n];
#pragma unroll
    for (int mi = 0; mi < 4; ++mi)
#pragma unroll
      for (int j = 0; j < 4; ++j) {
        int m = m0 + wm * 64 + mi * 16 + lg * 4 + j;
        out[(size_t)m * Cc + n] = acc[mi][ni][j] + bv;
      }
  }
}

// ---------------- launch ----------------
extern "C" void kernel_launch(void* const* d_in, const int* in_sizes, int n_in,
                              void* d_out, int out_size, void* d_ws, size_t ws_size,
                              hipStream_t stream) {
  const float* x  = (const float*)d_in[0];
  const float* wq = (const float*)d_in[1];
  const float* wk = (const float*)d_in[2];
  const float* wv = (const float*)d_in[3];
  const float* wp = (const float*)d_in[4];
  const float* bp = (const float*)d_in[5];
  float* out = (float*)d_out;

  char* ws = (char*)d_ws;
  __bf16* wqkvb = (__bf16*)ws;                    // 884736 B
  __bf16* wpb   = (__bf16*)(ws + 884736);         // 294912 B
  char*   dyn   = ws + 1179648;

  // per-chunk bytes = 4 * Mc*384*2 = Bc*786432  (xb aliases att)
  int Bc = 128;
  while (Bc > 1 && 1179648ull + (unsigned long long)Bc * 786432ull > (unsigned long long)ws_size)
    Bc >>= 1;
  const int Mc = Bc * 256;
  __bf16* xb  = (__bf16*)dyn;                             // Mc*384 bf16 (later reused as att)
  __bf16* att = xb;
  __bf16* qkv = (__bf16*)(dyn + (size_t)Mc * HD * 2);     // 3 planes of Mc*384 bf16

  prep_w<<<2304, 256, 0, stream>>>(wq, wk, wv, wp, wqkvb, wpb);

  for (int b0 = 0; b0 < 128; b0 += Bc) {
    const float* xc  = x + (size_t)b0 * Tt * Cc;
    float* outc      = out + (size_t)b0 * Tt * Cc;
    xcast<<<Bc * 48, 256, 0, stream>>>(xc, xb);
    gemm_qkv<<<dim3(Mc / 128, 9), 256, 0, stream>>>(xb, wqkvb, qkv, Mc);
    attn_k<<<Bc * Hh, 512, 0, stream>>>(qkv, qkv + (size_t)Mc * HD,
                                        qkv + (size_t)2 * Mc * HD, att);
    gemm_out<<<dim3(Mc / 128, 3), 256, 0, stream>>>(att, wpb, bp, outc, Mc);
  }
}